// Round 8
// baseline (122.346 us; speedup 1.0000x reference)
//
#include <hip/hip_runtime.h>
#include <hip/hip_bf16.h>
#include <stdint.h>

#define NTOK 8192
#define D_   1024
#define E_   8
#define MT   64
#define NT   128
#define BK   32
#define KSTEPS 64
#define MAX_TILES 192
#define BUF_S 6144   // shorts per LDS buffer: A 64*32=2048 + B 128*32=4096

typedef __attribute__((ext_vector_type(8))) short short8;
typedef __attribute__((ext_vector_type(4))) float f32x4;

__device__ inline unsigned short f2b(float f) {
    unsigned int u = __float_as_uint(f);
    unsigned int r = (u + 0x7fffu + ((u >> 16) & 1u)) >> 16;
    return (unsigned short)r;
}

// async global->LDS, 16B per lane; LDS dest = wave-uniform base + lane*16.
__device__ inline void gload16(const void* g, void* l) {
    __builtin_amdgcn_global_load_lds(
        (const __attribute__((address_space(1))) unsigned int*)(uintptr_t)g,
        (__attribute__((address_space(3))) unsigned int*)(unsigned int)(uintptr_t)l,
        16, 0, 0);
}

// ---------------- Phase 0+1 fused: We transpose (blocks 0..2047) || gating+cast (2048..2303) ----------------
__global__ __launch_bounds__(256) void prep_kernel(const float* __restrict__ We,
                                                   unsigned short* __restrict__ WeT,
                                                   const float* __restrict__ x,
                                                   const float* __restrict__ Wg,
                                                   int* __restrict__ g_tok,
                                                   float* __restrict__ wA_tok,
                                                   float* __restrict__ wB_tok,
                                                   unsigned short* __restrict__ Abf) {
    __shared__ __align__(16) float smem[8192];   // overlay: 64x65 tile | 8x1024 wgt
    int b = blockIdx.x;
    int t = threadIdx.x;
    if (b < 2048) {
        float (*tile)[65] = reinterpret_cast<float (*)[65]>(smem);
        int e = b >> 8, rem = b & 255;
        int m0 = (rem & 15) * 64, d0 = (rem >> 4) * 64;
        const float* src = We + ((size_t)e << 20);
        int r = t >> 4, c4 = (t & 15) * 4;
        #pragma unroll
        for (int i = 0; i < 4; i++) {
            int d = r + i * 16;
            float4 v = *reinterpret_cast<const float4*>(src + (size_t)(d0 + d) * D_ + m0 + c4);
            tile[d][c4 + 0] = v.x; tile[d][c4 + 1] = v.y;
            tile[d][c4 + 2] = v.z; tile[d][c4 + 3] = v.w;
        }
        __syncthreads();
        int m = t >> 2, dq = (t & 3) * 16;
        unsigned int pack[8];
        #pragma unroll
        for (int j = 0; j < 16; j += 2) {
            pack[j >> 1] = (unsigned int)f2b(tile[dq + j][m]) |
                           ((unsigned int)f2b(tile[dq + j + 1][m]) << 16);
        }
        uint4* dst = reinterpret_cast<uint4*>(WeT + ((size_t)e << 20) + (size_t)(m0 + m) * D_ + d0 + dq);
        dst[0] = make_uint4(pack[0], pack[1], pack[2], pack[3]);
        dst[1] = make_uint4(pack[4], pack[5], pack[6], pack[7]);
    } else {
        float* wgt = smem;   // transposed: wgt[e*1024 + d]
        for (int i = t; i < 8192; i += 256) wgt[(i & 7) * 1024 + (i >> 3)] = Wg[i];
        __syncthreads();
        int wave = t >> 6, lane = t & 63;
        int tok0 = (b - 2048) * 32 + wave * 8;

        for (int tki = 0; tki < 8; tki++) {
            int tok = tok0 + tki;
            const float* xr = x + (size_t)tok * D_;

            float4 xv[4];
            float acc[8] = {0.f, 0.f, 0.f, 0.f, 0.f, 0.f, 0.f, 0.f};
            #pragma unroll
            for (int i = 0; i < 4; i++) {
                int d0 = i * 256 + lane * 4;
                xv[i] = *reinterpret_cast<const float4*>(xr + d0);
                #pragma unroll
                for (int e = 0; e < 8; e++) {
                    float4 w = *reinterpret_cast<const float4*>(&wgt[e * 1024 + d0]);
                    acc[e] += xv[i].x * w.x + xv[i].y * w.y + xv[i].z * w.z + xv[i].w * w.w;
                }
            }
            #pragma unroll
            for (int e = 0; e < 8; e++)
                #pragma unroll
                for (int off = 32; off > 0; off >>= 1)
                    acc[e] += __shfl_xor(acc[e], off, 64);

            float best = acc[0]; int bi = 0;
            #pragma unroll
            for (int e = 1; e < 8; e++) { if (acc[e] > best) { best = acc[e]; bi = e; } }
            float second = -3.4e38f; int si = 0;
            #pragma unroll
            for (int e = 0; e < 8; e++) { if (e != bi && acc[e] > second) { second = acc[e]; si = e; } }
            float eb = __expf(second - best);
            eb = fmaxf(eb, 1e-20f);
            float w0 = 1.f / (1.f + eb);
            float w1 = eb / (1.f + eb);
            int ea, ebx; float wA, wB;
            if (bi < si) { ea = bi; ebx = si; wA = w0; wB = w1; }
            else         { ea = si; ebx = bi; wA = w1; wB = w0; }
            if (lane == 0) {
                g_tok[tok] = ea * 8 + ebx;
                wA_tok[tok] = wA;
                wB_tok[tok] = wB;
            }

            unsigned short* rowp = Abf + (size_t)tok * D_;
            #pragma unroll
            for (int i = 0; i < 4; i++) {
                int d0 = i * 256 + lane * 4;
                uint2 p;
                p.x = (unsigned)f2b(xv[i].x) | ((unsigned)f2b(xv[i].y) << 16);
                p.y = (unsigned)f2b(xv[i].z) | ((unsigned)f2b(xv[i].w) << 16);
                *reinterpret_cast<uint2*>(rowp + d0) = p;
            }
        }
    }
}

// ---------------- Phase 2: routing — 64 parallel blocks, deterministic stable compaction ----------------
__global__ __launch_bounds__(256) void route_kernel(const int* __restrict__ g_tok,
                                                    const float* __restrict__ wA_tok,
                                                    const float* __restrict__ wB_tok,
                                                    int* __restrict__ token_list,
                                                    float* __restrict__ wA_s,
                                                    float* __restrict__ wB_s,
                                                    int4* __restrict__ tile_desc,
                                                    int* __restrict__ n_tiles_out) {
    int g = blockIdx.x;    // 0..63
    int t = threadIdx.x;   // 0..255
    __shared__ int cnt[64];
    __shared__ int pfx[256];
    __shared__ int startg, tbase, tottiles;
    if (t < 64) cnt[t] = 0;
    __syncthreads();

    int base = t * 32;
    int gl[32];
    int my = 0;
    #pragma unroll
    for (int k = 0; k < 32; k++) {
        gl[k] = g_tok[base + k];
        my += (gl[k] == g);
    }
    #pragma unroll
    for (int k = 0; k < 32; k++) atomicAdd(&cnt[gl[k]], 1);
    pfx[t] = my;
    __syncthreads();

    if (t == 0) {
        int run = 0, tb = 0, tt = 0;
        for (int gg = 0; gg < 64; gg++) {
            int c = cnt[gg];
            int ntl = (c + MT - 1) / MT;
            if (gg < g) { run += c; tb += ntl; }
            tt += ntl;
        }
        startg = run; tbase = tb; tottiles = tt;
    }
    for (int off = 1; off < 256; off <<= 1) {
        int add = (t >= off) ? pfx[t - off] : 0;
        __syncthreads();
        pfx[t] += add;
        __syncthreads();
    }

    int pos = startg + pfx[t] - my;
    #pragma unroll
    for (int k = 0; k < 32; k++) {
        if (gl[k] == g) {
            int idx = base + k;
            token_list[pos] = idx;
            wA_s[pos] = wA_tok[idx];
            wB_s[pos] = wB_tok[idx];
            pos++;
        }
    }
    if (t == 0) {
        int c = cnt[g];
        int off2 = 0, ti = tbase;
        while (off2 < c) {
            int rows = (c - off2 < MT) ? (c - off2) : MT;
            tile_desc[ti++] = make_int4(startg + off2, rows, g >> 3, g & 7);
            off2 += MT;
        }
        if (g == 0) *n_tiles_out = tottiles;
    }
}

// ---------------- Phase 3: grouped GEMM — 2-wave blocks, 64x64/wave, BK=32, 6 blocks/CU ----------------
// Grid dim3(8, tiles): XCD = colblk -> per-XCD B slice = 2 MB (L2-resident).
// ks 0..31: expert ea; ks 32..63: expert ebx over same A (acc rescaled by wA/wB at switch, *wB at end).
__global__ __launch_bounds__(128, 3) void moe_gemm(const unsigned short* __restrict__ Abf,
                                                   const unsigned short* __restrict__ WeT,
                                                   const int* __restrict__ token_list,
                                                   const float* __restrict__ wA_s,
                                                   const float* __restrict__ wB_s,
                                                   const int4* __restrict__ tile_desc,
                                                   const int* __restrict__ n_tiles,
                                                   float* __restrict__ out) {
    int tile = blockIdx.y;
    if (tile >= *n_tiles) return;
    int4 dsc = tile_desc[tile];
    int loff = dsc.x, rows = dsc.y, ea = dsc.z, ebx = dsc.w;
    int ncol0 = blockIdx.x * NT;

    __shared__ __align__(16) unsigned short lds[2 * BUF_S];  // 24 KB
    __shared__ int tokOut[MT];
    __shared__ int tokStage[MT];
    __shared__ float rat[MT], wBsh[MT];

    int t = threadIdx.x;     // 0..127
    int wave = t >> 6, lane = t & 63;

    if (t < MT) {
        int idx = loff + ((t < rows) ? t : 0);
        int tk = token_list[idx];
        tokStage[t] = tk;
        tokOut[t] = (t < rows) ? tk : -1;
        float wa = wA_s[idx], wb = wB_s[idx];
        wBsh[t] = wb;
        rat[t] = wa / fmaxf(wb, 1e-30f);
    }
    __syncthreads();

    // ---- staging roles (swizzle folded into global source; LDS dest linear) ----
    // chunk = 16B. A: 256 chunks (64 rows x 4 slots), 2 gloads/thread.
    // phys slot s of row r holds logical slot s ^ ((r>>1)&3)  (2-way max on read, free)
    int ar0 = t >> 2;                 // rows 0..31
    int ar1 = 32 + (t >> 2);          // rows 32..63
    int as0 = (t & 3) ^ ((ar0 >> 1) & 3);
    int as1 = (t & 3) ^ ((ar1 >> 1) & 3);
    const unsigned short* asrc0 = Abf + (size_t)tokStage[ar0] * D_ + as0 * 8;
    const unsigned short* asrc1 = Abf + (size_t)tokStage[ar1] * D_ + as1 * 8;
    // B: 512 chunks (128 rows x 4 slots), 4 gloads/thread.
    const unsigned short* wbase = WeT + ((size_t)ea << 20);
    size_t ebd = ((size_t)(ebx - ea)) << 20;
    const unsigned short* bsrc[4];
    #pragma unroll
    for (int i = 0; i < 4; i++) {
        int rb = i * 32 + (t >> 2);
        int bs = (t & 3) ^ ((rb >> 1) & 3);
        bsrc[i] = wbase + (size_t)(ncol0 + rb) * D_ + bs * 8;
    }

    int wu = wave * 512;   // wave-uniform chunk base within each region (shorts)
    auto stage = [&](int ks, int buf) {
        unsigned short* base = &lds[buf * BUF_S];
        size_t ak = (size_t)((ks & 31) * BK);
        size_t bk = ak + ((ks < 32) ? 0 : ebd);
        gload16(asrc0 + ak, base + wu);
        gload16(asrc1 + ak, base + 1024 + wu);
        #pragma unroll
        for (int i = 0; i < 4; i++)
            gload16(bsrc[i] + bk, base + 2048 + i * 1024 + wu);
    };

    // ---- compute roles: wave owns all 64 rows x cols [wave*64, wave*64+64) ----
    int l15 = lane & 15, hi = lane >> 4;
    int q4 = hi * 4;
    int aoff[4], boff[4];
    #pragma unroll
    for (int m = 0; m < 4; m++) {
        int r = m * 16 + l15;
        aoff[m] = r * BK + ((hi ^ ((r >> 1) & 3)) << 3);
    }
    #pragma unroll
    for (int n = 0; n < 4; n++) {
        int r = wave * 64 + n * 16 + l15;
        boff[n] = 2048 + r * BK + ((hi ^ ((r >> 1) & 3)) << 3);
    }

    f32x4 acc[4][4];
    #pragma unroll
    for (int m = 0; m < 4; m++)
        #pragma unroll
        for (int n = 0; n < 4; n++) acc[m][n] = (f32x4){0.f, 0.f, 0.f, 0.f};

    stage(0, 0);
    for (int ks = 0; ks < KSTEPS; ++ks) {
        if (ks < KSTEPS - 1) {
            stage(ks + 1, (ks + 1) & 1);
            asm volatile("s_waitcnt vmcnt(6)" ::: "memory");
        } else {
            asm volatile("s_waitcnt vmcnt(0)" ::: "memory");
        }
        __builtin_amdgcn_s_barrier();
        if (ks == 32) {
            // expert switch: acc *= wA/wB per row; epilogue multiplies by wB
            #pragma unroll
            for (int m = 0; m < 4; m++) {
                #pragma unroll
                for (int j = 0; j < 4; j++) {
                    float rr = rat[m * 16 + q4 + j];
                    #pragma unroll
                    for (int n = 0; n < 4; n++) acc[m][n][j] *= rr;
                }
            }
        }
        const unsigned short* Ab = &lds[(ks & 1) * BUF_S];
        short8 a[4], bfr[4];
        #pragma unroll
        for (int m = 0; m < 4; m++)
            a[m] = *reinterpret_cast<const short8*>(&Ab[aoff[m]]);
        #pragma unroll
        for (int n = 0; n < 4; n++)
            bfr[n] = *reinterpret_cast<const short8*>(&Ab[boff[n]]);
        #pragma unroll
        for (int m = 0; m < 4; m++)
            #pragma unroll
            for (int n = 0; n < 4; n++)
                acc[m][n] = __builtin_amdgcn_mfma_f32_16x16x32_bf16(a[m], bfr[n], acc[m][n], 0, 0, 0);
        __builtin_amdgcn_s_barrier();   // readers done before next overwrite of the other buffer
    }

    // epilogue: single writer per out row; out = acc * wB
    #pragma unroll
    for (int m = 0; m < 4; m++) {
        #pragma unroll
        for (int n = 0; n < 4; n++) {
            int col = ncol0 + wave * 64 + n * 16 + l15;
            #pragma unroll
            for (int j = 0; j < 4; j++) {
                int r = m * 16 + q4 + j;
                int tk = tokOut[r];
                if (tk >= 0) out[(size_t)tk * D_ + col] = acc[m][n][j] * wBsh[r];
            }
        }
    }
}

extern "C" void kernel_launch(void* const* d_in, const int* in_sizes, int n_in,
                              void* d_out, int out_size, void* d_ws, size_t ws_size,
                              hipStream_t stream) {
    const float* x  = (const float*)d_in[0];
    const float* Wg = (const float*)d_in[1];
    const float* We = (const float*)d_in[2];
    float* out = (float*)d_out;

    size_t off = 0;
    auto alloc = [&](size_t bytes) -> void* {
        void* p = (char*)d_ws + off;
        off += (bytes + 255) & ~(size_t)255;
        return p;
    };
    unsigned short* WeT  = (unsigned short*)alloc((size_t)E_ * 1024 * 1024 * 2);  // 16 MB
    unsigned short* Abf  = (unsigned short*)alloc((size_t)NTOK * D_ * 2);         // 16.8 MB
    int*   g_tok      = (int*)  alloc(NTOK * 4);
    float* wA_tok     = (float*)alloc(NTOK * 4);
    float* wB_tok     = (float*)alloc(NTOK * 4);
    int*   token_list = (int*)  alloc(NTOK * 4);
    float* wA_s       = (float*)alloc(NTOK * 4);
    float* wB_s       = (float*)alloc(NTOK * 4);
    int4*  tile_desc  = (int4*) alloc(MAX_TILES * 16);
    int*   n_tiles    = (int*)  alloc(4);

    prep_kernel<<<2048 + 256, 256, 0, stream>>>(We, WeT, x, Wg, g_tok, wA_tok, wB_tok, Abf);
    route_kernel<<<64, 256, 0, stream>>>(g_tok, wA_tok, wB_tok,
                                         token_list, wA_s, wB_s, tile_desc, n_tiles);
    moe_gemm<<<dim3(8, MAX_TILES), 128, 0, stream>>>(Abf, WeT, token_list, wA_s, wB_s,
                                                     tile_desc, n_tiles, out);
}

// Round 9
// 101.762 us; speedup vs baseline: 1.2023x; 1.2023x over previous
//
#include <hip/hip_runtime.h>
#include <hip/hip_bf16.h>
#include <stdint.h>

#define NTOK 8192
#define D_   1024
#define E_   8
#define MT   128
#define NT   128
#define BK   64
#define KSTEPS 32     // 16 per expert half
#define MAX_TILES 96

typedef __attribute__((ext_vector_type(8))) short short8;
typedef __attribute__((ext_vector_type(4))) float f32x4;

__device__ inline unsigned short f2b(float f) {
    unsigned int u = __float_as_uint(f);
    unsigned int r = (u + 0x7fffu + ((u >> 16) & 1u)) >> 16;
    return (unsigned short)r;
}

// async global->LDS, 16B per lane; LDS dest = wave-uniform base + lane*16.
__device__ inline void gload16(const void* g, void* l) {
    __builtin_amdgcn_global_load_lds(
        (const __attribute__((address_space(1))) unsigned int*)(uintptr_t)g,
        (__attribute__((address_space(3))) unsigned int*)(unsigned int)(uintptr_t)l,
        16, 0, 0);
}

// ---------------- Phase 0+1 fused: We transpose (blocks 0..2047) || gating+cast (2048..2303) ----------------
__global__ __launch_bounds__(256) void prep_kernel(const float* __restrict__ We,
                                                   unsigned short* __restrict__ WeT,
                                                   const float* __restrict__ x,
                                                   const float* __restrict__ Wg,
                                                   int* __restrict__ g_tok,
                                                   float* __restrict__ wA_tok,
                                                   float* __restrict__ wB_tok,
                                                   unsigned short* __restrict__ Abf) {
    __shared__ __align__(16) float smem[8192];   // overlay: 64x65 tile | 8x1024 wgt
    int b = blockIdx.x;
    int t = threadIdx.x;
    if (b < 2048) {
        float (*tile)[65] = reinterpret_cast<float (*)[65]>(smem);
        int e = b >> 8, rem = b & 255;
        int m0 = (rem & 15) * 64, d0 = (rem >> 4) * 64;
        const float* src = We + ((size_t)e << 20);
        int r = t >> 4, c4 = (t & 15) * 4;
        #pragma unroll
        for (int i = 0; i < 4; i++) {
            int d = r + i * 16;
            float4 v = *reinterpret_cast<const float4*>(src + (size_t)(d0 + d) * D_ + m0 + c4);
            tile[d][c4 + 0] = v.x; tile[d][c4 + 1] = v.y;
            tile[d][c4 + 2] = v.z; tile[d][c4 + 3] = v.w;
        }
        __syncthreads();
        int m = t >> 2, dq = (t & 3) * 16;
        unsigned int pack[8];
        #pragma unroll
        for (int j = 0; j < 16; j += 2) {
            pack[j >> 1] = (unsigned int)f2b(tile[dq + j][m]) |
                           ((unsigned int)f2b(tile[dq + j + 1][m]) << 16);
        }
        uint4* dst = reinterpret_cast<uint4*>(WeT + ((size_t)e << 20) + (size_t)(m0 + m) * D_ + d0 + dq);
        dst[0] = make_uint4(pack[0], pack[1], pack[2], pack[3]);
        dst[1] = make_uint4(pack[4], pack[5], pack[6], pack[7]);
    } else {
        float* wgt = smem;   // transposed: wgt[e*1024 + d]
        for (int i = t; i < 8192; i += 256) wgt[(i & 7) * 1024 + (i >> 3)] = Wg[i];
        __syncthreads();
        int wave = t >> 6, lane = t & 63;
        int tok0 = (b - 2048) * 32 + wave * 8;

        for (int tki = 0; tki < 8; tki++) {
            int tok = tok0 + tki;
            const float* xr = x + (size_t)tok * D_;

            float4 xv[4];
            float acc[8] = {0.f, 0.f, 0.f, 0.f, 0.f, 0.f, 0.f, 0.f};
            #pragma unroll
            for (int i = 0; i < 4; i++) {
                int d0 = i * 256 + lane * 4;
                xv[i] = *reinterpret_cast<const float4*>(xr + d0);
                #pragma unroll
                for (int e = 0; e < 8; e++) {
                    float4 w = *reinterpret_cast<const float4*>(&wgt[e * 1024 + d0]);
                    acc[e] += xv[i].x * w.x + xv[i].y * w.y + xv[i].z * w.z + xv[i].w * w.w;
                }
            }
            #pragma unroll
            for (int e = 0; e < 8; e++)
                #pragma unroll
                for (int off = 32; off > 0; off >>= 1)
                    acc[e] += __shfl_xor(acc[e], off, 64);

            float best = acc[0]; int bi = 0;
            #pragma unroll
            for (int e = 1; e < 8; e++) { if (acc[e] > best) { best = acc[e]; bi = e; } }
            float second = -3.4e38f; int si = 0;
            #pragma unroll
            for (int e = 0; e < 8; e++) { if (e != bi && acc[e] > second) { second = acc[e]; si = e; } }
            float eb = __expf(second - best);
            eb = fmaxf(eb, 1e-20f);
            float w0 = 1.f / (1.f + eb);
            float w1 = eb / (1.f + eb);
            int ea, ebx; float wA, wB;
            if (bi < si) { ea = bi; ebx = si; wA = w0; wB = w1; }
            else         { ea = si; ebx = bi; wA = w1; wB = w0; }
            if (lane == 0) {
                g_tok[tok] = ea * 8 + ebx;
                wA_tok[tok] = wA;
                wB_tok[tok] = wB;
            }

            unsigned short* rowp = Abf + (size_t)tok * D_;
            #pragma unroll
            for (int i = 0; i < 4; i++) {
                int d0 = i * 256 + lane * 4;
                uint2 p;
                p.x = (unsigned)f2b(xv[i].x) | ((unsigned)f2b(xv[i].y) << 16);
                p.y = (unsigned)f2b(xv[i].z) | ((unsigned)f2b(xv[i].w) << 16);
                *reinterpret_cast<uint2*>(rowp + d0) = p;
            }
        }
    }
}

// ---------------- Phase 2: routing — 64 parallel blocks, deterministic stable compaction ----------------
__global__ __launch_bounds__(256) void route_kernel(const int* __restrict__ g_tok,
                                                    const float* __restrict__ wA_tok,
                                                    const float* __restrict__ wB_tok,
                                                    int* __restrict__ token_list,
                                                    float* __restrict__ wA_s,
                                                    float* __restrict__ wB_s,
                                                    int4* __restrict__ tile_desc,
                                                    int* __restrict__ n_tiles_out) {
    int g = blockIdx.x;    // 0..63
    int t = threadIdx.x;   // 0..255
    __shared__ int cnt[64];
    __shared__ int pfx[256];
    __shared__ int startg, tbase, tottiles;
    if (t < 64) cnt[t] = 0;
    __syncthreads();

    int base = t * 32;
    int gl[32];
    int my = 0;
    #pragma unroll
    for (int k = 0; k < 32; k++) {
        gl[k] = g_tok[base + k];
        my += (gl[k] == g);
    }
    #pragma unroll
    for (int k = 0; k < 32; k++) atomicAdd(&cnt[gl[k]], 1);
    pfx[t] = my;
    __syncthreads();

    if (t == 0) {
        int run = 0, tb = 0, tt = 0;
        for (int gg = 0; gg < 64; gg++) {
            int c = cnt[gg];
            int ntl = (c + MT - 1) / MT;
            if (gg < g) { run += c; tb += ntl; }
            tt += ntl;
        }
        startg = run; tbase = tb; tottiles = tt;
    }
    for (int off = 1; off < 256; off <<= 1) {
        int add = (t >= off) ? pfx[t - off] : 0;
        __syncthreads();
        pfx[t] += add;
        __syncthreads();
    }

    int pos = startg + pfx[t] - my;
    #pragma unroll
    for (int k = 0; k < 32; k++) {
        if (gl[k] == g) {
            int idx = base + k;
            token_list[pos] = idx;
            wA_s[pos] = wA_tok[idx];
            wB_s[pos] = wB_tok[idx];
            pos++;
        }
    }
    if (t == 0) {
        int c = cnt[g];
        int off2 = 0, ti = tbase;
        while (off2 < c) {
            int rows = (c - off2 < MT) ? (c - off2) : MT;
            tile_desc[ti++] = make_int4(startg + off2, rows, g >> 3, g & 7);
            off2 += MT;
        }
        if (g == 0) *n_tiles_out = tottiles;
    }
}

// ---------------- Phase 3: grouped GEMM — m97 clone: 128x128 tile, BK=64, 1 buffer, 4 blocks/CU ----------------
// Grid dim3(8, tiles): XCD = colblk -> per-XCD B slice = 2 MB (L2-resident).
// ks 0..15: expert ea; ks 16..31: expert ebx over SAME A (acc rescaled by wA/wB at switch, *wB at end).
__global__ __launch_bounds__(256, 4) void moe_gemm(const unsigned short* __restrict__ Abf,
                                                   const unsigned short* __restrict__ WeT,
                                                   const int* __restrict__ token_list,
                                                   const float* __restrict__ wA_s,
                                                   const float* __restrict__ wB_s,
                                                   const int4* __restrict__ tile_desc,
                                                   const int* __restrict__ n_tiles,
                                                   float* __restrict__ out) {
    int tile = blockIdx.y;
    if (tile >= *n_tiles) return;
    int4 dsc = tile_desc[tile];
    int loff = dsc.x, rows = dsc.y, ea = dsc.z, ebx = dsc.w;
    int ncol0 = blockIdx.x * NT;

    __shared__ __align__(16) unsigned short As[MT * BK];   // 16 KB
    __shared__ __align__(16) unsigned short Bs[NT * BK];   // 16 KB
    __shared__ int tokOut[MT];
    __shared__ int tokStage[MT];
    __shared__ float rat[MT], wBsh[MT];

    int t = threadIdx.x;
    int wave = t >> 6, lane = t & 63;

    if (t < MT) {
        int idx = loff + ((t < rows) ? t : 0);
        int tk = token_list[idx];
        tokStage[t] = tk;
        tokOut[t] = (t < rows) ? tk : -1;
        float wa = wA_s[idx], wb = wB_s[idx];
        wBsh[t] = wb;
        rat[t] = wa / fmaxf(wb, 1e-30f);
    }
    __syncthreads();

    // ---- staging roles: chunk g = t + i*256 (i=0..3); row = g>>3, phys slot g&7
    // holds logical chunk (g&7)^(row&7). Swizzle folded into global source; LDS linear.
    const unsigned short* asrc[4];
    const unsigned short* bsrc[4];
    const unsigned short* wbase = WeT + ((size_t)ea << 20);
    size_t ebd = ((size_t)(ebx - ea)) << 20;
    #pragma unroll
    for (int i = 0; i < 4; i++) {
        int g = t + i * 256;
        int row = g >> 3;
        int c = (g & 7) ^ (row & 7);
        asrc[i] = Abf + (size_t)tokStage[row] * D_ + c * 8;
        bsrc[i] = wbase + (size_t)(ncol0 + row) * D_ + c * 8;
    }

    auto stage = [&](int ks) {
        int k0 = (ks & 15) * BK;                       // shorts
        size_t bo = (size_t)k0 + ((ks < 16) ? 0 : ebd);
        #pragma unroll
        for (int i = 0; i < 4; i++) {
            int dbase = (i * 256 + wave * 64) * 8;     // wave-uniform; HW adds lane*16B
            gload16(asrc[i] + k0, As + dbase);
            gload16(bsrc[i] + bo, Bs + dbase);
        }
    };

    // ---- compute roles: 2x2 wave grid, wave-tile 64x64 ----
    int wm = (wave >> 1) * 64, wn = (wave & 1) * 64;
    int l15 = lane & 15, hi = lane >> 4, q4 = hi * 4;
    int aoff[2][4], boff[2][4];
    #pragma unroll
    for (int ksub = 0; ksub < 2; ksub++) {
        #pragma unroll
        for (int m = 0; m < 4; m++) {
            int r = wm + m * 16 + l15;
            aoff[ksub][m] = r * BK + (((hi + 4 * ksub) ^ (r & 7)) << 3);
            int rb = wn + m * 16 + l15;
            boff[ksub][m] = rb * BK + (((hi + 4 * ksub) ^ (rb & 7)) << 3);
        }
    }

    f32x4 acc[4][4];
    #pragma unroll
    for (int m = 0; m < 4; m++)
        #pragma unroll
        for (int n = 0; n < 4; n++) acc[m][n] = (f32x4){0.f, 0.f, 0.f, 0.f};

    for (int ks = 0; ks < KSTEPS; ++ks) {
        stage(ks);
        asm volatile("s_waitcnt vmcnt(0)" ::: "memory");
        __builtin_amdgcn_s_barrier();
        if (ks == 16) {
            // expert switch: acc *= wA/wB per row; epilogue multiplies by wB
            #pragma unroll
            for (int m = 0; m < 4; m++) {
                #pragma unroll
                for (int j = 0; j < 4; j++) {
                    float rr = rat[wm + m * 16 + q4 + j];
                    #pragma unroll
                    for (int n = 0; n < 4; n++) acc[m][n][j] *= rr;
                }
            }
        }
        #pragma unroll
        for (int ksub = 0; ksub < 2; ++ksub) {
            short8 a[4], bfr[4];
            #pragma unroll
            for (int m = 0; m < 4; m++) {
                a[m] = *reinterpret_cast<const short8*>(&As[aoff[ksub][m]]);
                bfr[m] = *reinterpret_cast<const short8*>(&Bs[boff[ksub][m]]);
            }
            #pragma unroll
            for (int m = 0; m < 4; m++)
                #pragma unroll
                for (int n = 0; n < 4; n++)
                    acc[m][n] = __builtin_amdgcn_mfma_f32_16x16x32_bf16(a[m], bfr[n], acc[m][n], 0, 0, 0);
        }
        __builtin_amdgcn_s_barrier();   // all reads done before next stage overwrites
    }

    // epilogue: single writer per out row; out = acc * wB
    #pragma unroll
    for (int m = 0; m < 4; m++) {
        #pragma unroll
        for (int n = 0; n < 4; n++) {
            int col = ncol0 + wn + n * 16 + l15;
            #pragma unroll
            for (int j = 0; j < 4; j++) {
                int r = wm + m * 16 + q4 + j;
                int tk = tokOut[r];
                if (tk >= 0) out[(size_t)tk * D_ + col] = acc[m][n][j] * wBsh[r];
            }
        }
    }
}

extern "C" void kernel_launch(void* const* d_in, const int* in_sizes, int n_in,
                              void* d_out, int out_size, void* d_ws, size_t ws_size,
                              hipStream_t stream) {
    const float* x  = (const float*)d_in[0];
    const float* Wg = (const float*)d_in[1];
    const float* We = (const float*)d_in[2];
    float* out = (float*)d_out;

    size_t off = 0;
    auto alloc = [&](size_t bytes) -> void* {
        void* p = (char*)d_ws + off;
        off += (bytes + 255) & ~(size_t)255;
        return p;
    };
    unsigned short* WeT  = (unsigned short*)alloc((size_t)E_ * 1024 * 1024 * 2);  // 16 MB
    unsigned short* Abf  = (unsigned short*)alloc((size_t)NTOK * D_ * 2);         // 16.8 MB
    int*   g_tok      = (int*)  alloc(NTOK * 4);
    float* wA_tok     = (float*)alloc(NTOK * 4);
    float* wB_tok     = (float*)alloc(NTOK * 4);
    int*   token_list = (int*)  alloc(NTOK * 4);
    float* wA_s       = (float*)alloc(NTOK * 4);
    float* wB_s       = (float*)alloc(NTOK * 4);
    int4*  tile_desc  = (int4*) alloc(MAX_TILES * 16);
    int*   n_tiles    = (int*)  alloc(4);

    prep_kernel<<<2048 + 256, 256, 0, stream>>>(We, WeT, x, Wg, g_tok, wA_tok, wB_tok, Abf);
    route_kernel<<<64, 256, 0, stream>>>(g_tok, wA_tok, wB_tok,
                                         token_list, wA_s, wB_s, tile_desc, n_tiles);
    moe_gemm<<<dim3(8, MAX_TILES), 256, 0, stream>>>(Abf, WeT, token_list, wA_s, wB_s,
                                                     tile_desc, n_tiles, out);
}

// Round 10
// 100.467 us; speedup vs baseline: 1.2178x; 1.0129x over previous
//
#include <hip/hip_runtime.h>
#include <hip/hip_bf16.h>
#include <stdint.h>

#define NTOK 8192
#define D_   1024
#define E_   8
#define MT   128
#define NT   128
#define BK   64
#define KSTEPS 32     // 16 per expert half
#define MAX_TILES 96

typedef __attribute__((ext_vector_type(8))) short short8;
typedef __attribute__((ext_vector_type(4))) float f32x4;

__device__ inline unsigned short f2b(float f) {
    unsigned int u = __float_as_uint(f);
    unsigned int r = (u + 0x7fffu + ((u >> 16) & 1u)) >> 16;
    return (unsigned short)r;
}

// async global->LDS, 16B per lane; LDS dest = wave-uniform base + lane*16.
__device__ inline void gload16(const void* g, void* l) {
    __builtin_amdgcn_global_load_lds(
        (const __attribute__((address_space(1))) unsigned int*)(uintptr_t)g,
        (__attribute__((address_space(3))) unsigned int*)(unsigned int)(uintptr_t)l,
        16, 0, 0);
}

// ---------------- Phase 0+1 fused: gating+cast (blocks 0..1023, FIRST) || We transpose (1024..3071) ----------------
__global__ __launch_bounds__(256) void prep_kernel(const float* __restrict__ We,
                                                   unsigned short* __restrict__ WeT,
                                                   const float* __restrict__ x,
                                                   const float* __restrict__ Wg,
                                                   int* __restrict__ g_tok,
                                                   float* __restrict__ wA_tok,
                                                   float* __restrict__ wB_tok,
                                                   unsigned short* __restrict__ Abf) {
    __shared__ __align__(16) float smem[8192];   // overlay: 8x1024 wgt | 64x65 tile
    int b = blockIdx.x;
    int t = threadIdx.x;
    if (b < 1024) {
        // ---- gating + unweighted bf16 cast; 8 tokens per block, 2 per wave ----
        float* wgt = smem;   // transposed: wgt[e*1024 + d]
        for (int i = t; i < 8192; i += 256) wgt[(i & 7) * 1024 + (i >> 3)] = Wg[i];
        __syncthreads();
        int wave = t >> 6, lane = t & 63;
        int tok0 = b * 8 + wave * 2;

        for (int tki = 0; tki < 2; tki++) {
            int tok = tok0 + tki;
            const float* xr = x + (size_t)tok * D_;

            float4 xv[4];
            float acc[8] = {0.f, 0.f, 0.f, 0.f, 0.f, 0.f, 0.f, 0.f};
            #pragma unroll
            for (int i = 0; i < 4; i++) {
                int d0 = i * 256 + lane * 4;
                xv[i] = *reinterpret_cast<const float4*>(xr + d0);
                #pragma unroll
                for (int e = 0; e < 8; e++) {
                    float4 w = *reinterpret_cast<const float4*>(&wgt[e * 1024 + d0]);
                    acc[e] += xv[i].x * w.x + xv[i].y * w.y + xv[i].z * w.z + xv[i].w * w.w;
                }
            }
            #pragma unroll
            for (int e = 0; e < 8; e++)
                #pragma unroll
                for (int off = 32; off > 0; off >>= 1)
                    acc[e] += __shfl_xor(acc[e], off, 64);

            float best = acc[0]; int bi = 0;
            #pragma unroll
            for (int e = 1; e < 8; e++) { if (acc[e] > best) { best = acc[e]; bi = e; } }
            float second = -3.4e38f; int si = 0;
            #pragma unroll
            for (int e = 0; e < 8; e++) { if (e != bi && acc[e] > second) { second = acc[e]; si = e; } }
            float eb = __expf(second - best);
            eb = fmaxf(eb, 1e-20f);
            float w0 = 1.f / (1.f + eb);
            float w1 = eb / (1.f + eb);
            int ea, ebx; float wA, wB;
            if (bi < si) { ea = bi; ebx = si; wA = w0; wB = w1; }
            else         { ea = si; ebx = bi; wA = w1; wB = w0; }
            if (lane == 0) {
                g_tok[tok] = ea * 8 + ebx;
                wA_tok[tok] = wA;
                wB_tok[tok] = wB;
            }

            unsigned short* rowp = Abf + (size_t)tok * D_;
            #pragma unroll
            for (int i = 0; i < 4; i++) {
                int d0 = i * 256 + lane * 4;
                uint2 p;
                p.x = (unsigned)f2b(xv[i].x) | ((unsigned)f2b(xv[i].y) << 16);
                p.y = (unsigned)f2b(xv[i].z) | ((unsigned)f2b(xv[i].w) << 16);
                *reinterpret_cast<uint2*>(rowp + d0) = p;
            }
        }
    } else {
        // ---- We (E,D,D) f32 -> WeT (E,M,D) bf16 ----
        float (*tile)[65] = reinterpret_cast<float (*)[65]>(smem);
        int bb = b - 1024;
        int e = bb >> 8, rem = bb & 255;
        int m0 = (rem & 15) * 64, d0 = (rem >> 4) * 64;
        const float* src = We + ((size_t)e << 20);
        int r = t >> 4, c4 = (t & 15) * 4;
        #pragma unroll
        for (int i = 0; i < 4; i++) {
            int d = r + i * 16;
            float4 v = *reinterpret_cast<const float4*>(src + (size_t)(d0 + d) * D_ + m0 + c4);
            tile[d][c4 + 0] = v.x; tile[d][c4 + 1] = v.y;
            tile[d][c4 + 2] = v.z; tile[d][c4 + 3] = v.w;
        }
        __syncthreads();
        int m = t >> 2, dq = (t & 3) * 16;
        unsigned int pack[8];
        #pragma unroll
        for (int j = 0; j < 16; j += 2) {
            pack[j >> 1] = (unsigned int)f2b(tile[dq + j][m]) |
                           ((unsigned int)f2b(tile[dq + j + 1][m]) << 16);
        }
        uint4* dst = reinterpret_cast<uint4*>(WeT + ((size_t)e << 20) + (size_t)(m0 + m) * D_ + d0 + dq);
        dst[0] = make_uint4(pack[0], pack[1], pack[2], pack[3]);
        dst[1] = make_uint4(pack[4], pack[5], pack[6], pack[7]);
    }
}

// ---------------- Phase 2: routing — 64 parallel blocks, mixed 128/64 tiles ----------------
__global__ __launch_bounds__(256) void route_kernel(const int* __restrict__ g_tok,
                                                    const float* __restrict__ wA_tok,
                                                    const float* __restrict__ wB_tok,
                                                    int* __restrict__ token_list,
                                                    float* __restrict__ wA_s,
                                                    float* __restrict__ wB_s,
                                                    int4* __restrict__ tile_desc,
                                                    int* __restrict__ n_tiles_out) {
    int g = blockIdx.x;    // 0..63
    int t = threadIdx.x;   // 0..255
    __shared__ int cnt[64];
    __shared__ int pfx[256];
    __shared__ int startg, tbase, tottiles;
    if (t < 64) cnt[t] = 0;
    __syncthreads();

    int base = t * 32;
    int gl[32];
    int my = 0;
    #pragma unroll
    for (int k = 0; k < 32; k++) {
        gl[k] = g_tok[base + k];
        my += (gl[k] == g);
    }
    #pragma unroll
    for (int k = 0; k < 32; k++) atomicAdd(&cnt[gl[k]], 1);
    pfx[t] = my;
    __syncthreads();

    if (t == 0) {
        int run = 0, tb = 0, tt = 0;
        for (int gg = 0; gg < 64; gg++) {
            int c = cnt[gg];
            int n = 0, rem = c;
            while (rem > 64) { int take = (rem >= 128) ? 128 : rem; rem -= take; n++; }
            if (rem > 0) n++;
            if (gg < g) { run += c; tb += n; }
            tt += n;
        }
        startg = run; tbase = tb; tottiles = tt;
    }
    for (int off = 1; off < 256; off <<= 1) {
        int add = (t >= off) ? pfx[t - off] : 0;
        __syncthreads();
        pfx[t] += add;
        __syncthreads();
    }

    int pos = startg + pfx[t] - my;
    #pragma unroll
    for (int k = 0; k < 32; k++) {
        if (gl[k] == g) {
            int idx = base + k;
            token_list[pos] = idx;
            wA_s[pos] = wA_tok[idx];
            wB_s[pos] = wB_tok[idx];
            pos++;
        }
    }
    if (t == 0) {
        int rem = cnt[g], off2 = 0, ti = tbase;
        while (rem > 64) {
            int take = (rem >= 128) ? 128 : rem;
            tile_desc[ti++] = make_int4(startg + off2, take, g >> 3, g & 7);
            off2 += take; rem -= take;
        }
        if (rem > 0) tile_desc[ti++] = make_int4(startg + off2, rem, g >> 3, g & 7);
        if (g == 0) *n_tiles_out = tottiles;
    }
}

// ---------------- Phase 3: grouped GEMM — mixed tiles: 128x128 (R9-verified) / 64x128 tail ----------------
// Grid dim3(8, tiles): XCD = colblk -> per-XCD B slice = 2 MB (L2-resident).
// ks 0..15: expert ea; ks 16..31: expert ebx over SAME A (acc rescaled by wA/wB at switch, *wB at end).
__global__ __launch_bounds__(256, 4) void moe_gemm(const unsigned short* __restrict__ Abf,
                                                   const unsigned short* __restrict__ WeT,
                                                   const int* __restrict__ token_list,
                                                   const float* __restrict__ wA_s,
                                                   const float* __restrict__ wB_s,
                                                   const int4* __restrict__ tile_desc,
                                                   const int* __restrict__ n_tiles,
                                                   float* __restrict__ out) {
    int tile = blockIdx.y;
    if (tile >= *n_tiles) return;
    int4 dsc = tile_desc[tile];
    int loff = dsc.x, rows = dsc.y, ea = dsc.z, ebx = dsc.w;
    int ncol0 = blockIdx.x * NT;

    __shared__ __align__(16) unsigned short As[MT * BK];   // 16 KB
    __shared__ __align__(16) unsigned short Bs[NT * BK];   // 16 KB
    __shared__ int tokOut[MT];
    __shared__ int tokStage[MT];
    __shared__ float rat[MT], wBsh[MT];

    int t = threadIdx.x;
    int wave = t >> 6, lane = t & 63;

    if (t < MT) {
        int idx = loff + ((t < rows) ? t : 0);
        int tk = token_list[idx];
        tokStage[t] = tk;
        tokOut[t] = (t < rows) ? tk : -1;
        float wa = wA_s[idx], wb = wB_s[idx];
        wBsh[t] = wb;
        rat[t] = wa / fmaxf(wb, 1e-30f);
    }
    __syncthreads();

    const unsigned short* wbase = WeT + ((size_t)ea << 20);
    size_t ebd = ((size_t)(ebx - ea)) << 20;
    int l15 = lane & 15, hi = lane >> 4, q4 = hi * 4;

    if (rows > 64) {
        // ================= FULL PATH: 128x128, wave-tile 64x64 (R9-verified) =================
        const unsigned short* asrc[4];
        const unsigned short* bsrc[4];
        #pragma unroll
        for (int i = 0; i < 4; i++) {
            int g = t + i * 256;
            int row = g >> 3;
            int c = (g & 7) ^ (row & 7);
            asrc[i] = Abf + (size_t)tokStage[row] * D_ + c * 8;
            bsrc[i] = wbase + (size_t)(ncol0 + row) * D_ + c * 8;
        }

        int wm = (wave >> 1) * 64, wn = (wave & 1) * 64;
        int aoff[2][4], boff[2][4];
        #pragma unroll
        for (int ksub = 0; ksub < 2; ksub++) {
            #pragma unroll
            for (int m = 0; m < 4; m++) {
                int r = wm + m * 16 + l15;
                aoff[ksub][m] = r * BK + (((hi + 4 * ksub) ^ (r & 7)) << 3);
                int rb = wn + m * 16 + l15;
                boff[ksub][m] = rb * BK + (((hi + 4 * ksub) ^ (rb & 7)) << 3);
            }
        }

        f32x4 acc[4][4];
        #pragma unroll
        for (int m = 0; m < 4; m++)
            #pragma unroll
            for (int n = 0; n < 4; n++) acc[m][n] = (f32x4){0.f, 0.f, 0.f, 0.f};

        for (int ks = 0; ks < KSTEPS; ++ks) {
            int k0 = (ks & 15) * BK;
            size_t bo = (size_t)k0 + ((ks < 16) ? 0 : ebd);
            #pragma unroll
            for (int i = 0; i < 4; i++) {
                int dbase = (i * 256 + wave * 64) * 8;
                gload16(asrc[i] + k0, As + dbase);
                gload16(bsrc[i] + bo, Bs + dbase);
            }
            asm volatile("s_waitcnt vmcnt(0)" ::: "memory");
            __builtin_amdgcn_s_barrier();
            if (ks == 16) {
                #pragma unroll
                for (int m = 0; m < 4; m++) {
                    #pragma unroll
                    for (int j = 0; j < 4; j++) {
                        float rr = rat[wm + m * 16 + q4 + j];
                        #pragma unroll
                        for (int n = 0; n < 4; n++) acc[m][n][j] *= rr;
                    }
                }
            }
            #pragma unroll
            for (int ksub = 0; ksub < 2; ++ksub) {
                short8 a[4], bfr[4];
                #pragma unroll
                for (int m = 0; m < 4; m++) {
                    a[m] = *reinterpret_cast<const short8*>(&As[aoff[ksub][m]]);
                    bfr[m] = *reinterpret_cast<const short8*>(&Bs[boff[ksub][m]]);
                }
                #pragma unroll
                for (int m = 0; m < 4; m++)
                    #pragma unroll
                    for (int n = 0; n < 4; n++)
                        acc[m][n] = __builtin_amdgcn_mfma_f32_16x16x32_bf16(a[m], bfr[n], acc[m][n], 0, 0, 0);
            }
            __builtin_amdgcn_s_barrier();
        }

        #pragma unroll
        for (int m = 0; m < 4; m++) {
            #pragma unroll
            for (int n = 0; n < 4; n++) {
                int col = ncol0 + wn + n * 16 + l15;
                #pragma unroll
                for (int j = 0; j < 4; j++) {
                    int r = wm + m * 16 + q4 + j;
                    int tk = tokOut[r];
                    if (tk >= 0) out[(size_t)tk * D_ + col] = acc[m][n][j] * wBsh[r];
                }
            }
        }
    } else {
        // ================= TAIL PATH: 64x128, wave-tile 32x64 =================
        const unsigned short* asrcT[2];
        const unsigned short* bsrcT[4];
        #pragma unroll
        for (int i = 0; i < 2; i++) {
            int g = t + i * 256;
            int row = g >> 3;
            int c = (g & 7) ^ (row & 7);
            asrcT[i] = Abf + (size_t)tokStage[row] * D_ + c * 8;
        }
        #pragma unroll
        for (int i = 0; i < 4; i++) {
            int g = t + i * 256;
            int row = g >> 3;
            int c = (g & 7) ^ (row & 7);
            bsrcT[i] = wbase + (size_t)(ncol0 + row) * D_ + c * 8;
        }

        int wm = (wave >> 1) * 32, wn = (wave & 1) * 64;
        int aoff[2][2], boff[2][4];
        #pragma unroll
        for (int ksub = 0; ksub < 2; ksub++) {
            #pragma unroll
            for (int m = 0; m < 2; m++) {
                int r = wm + m * 16 + l15;
                aoff[ksub][m] = r * BK + (((hi + 4 * ksub) ^ (r & 7)) << 3);
            }
            #pragma unroll
            for (int n = 0; n < 4; n++) {
                int rb = wn + n * 16 + l15;
                boff[ksub][n] = rb * BK + (((hi + 4 * ksub) ^ (rb & 7)) << 3);
            }
        }

        f32x4 acc[2][4];
        #pragma unroll
        for (int m = 0; m < 2; m++)
            #pragma unroll
            for (int n = 0; n < 4; n++) acc[m][n] = (f32x4){0.f, 0.f, 0.f, 0.f};

        for (int ks = 0; ks < KSTEPS; ++ks) {
            int k0 = (ks & 15) * BK;
            size_t bo = (size_t)k0 + ((ks < 16) ? 0 : ebd);
            #pragma unroll
            for (int i = 0; i < 2; i++)
                gload16(asrcT[i] + k0, As + (i * 256 + wave * 64) * 8);
            #pragma unroll
            for (int i = 0; i < 4; i++)
                gload16(bsrcT[i] + bo, Bs + (i * 256 + wave * 64) * 8);
            asm volatile("s_waitcnt vmcnt(0)" ::: "memory");
            __builtin_amdgcn_s_barrier();
            if (ks == 16) {
                #pragma unroll
                for (int m = 0; m < 2; m++) {
                    #pragma unroll
                    for (int j = 0; j < 4; j++) {
                        float rr = rat[wm + m * 16 + q4 + j];
                        #pragma unroll
                        for (int n = 0; n < 4; n++) acc[m][n][j] *= rr;
                    }
                }
            }
            #pragma unroll
            for (int ksub = 0; ksub < 2; ++ksub) {
                short8 a[2], bfr[4];
                #pragma unroll
                for (int m = 0; m < 2; m++)
                    a[m] = *reinterpret_cast<const short8*>(&As[aoff[ksub][m]]);
                #pragma unroll
                for (int n = 0; n < 4; n++)
                    bfr[n] = *reinterpret_cast<const short8*>(&Bs[boff[ksub][n]]);
                #pragma unroll
                for (int m = 0; m < 2; m++)
                    #pragma unroll
                    for (int n = 0; n < 4; n++)
                        acc[m][n] = __builtin_amdgcn_mfma_f32_16x16x32_bf16(a[m], bfr[n], acc[m][n], 0, 0, 0);
            }
            __builtin_amdgcn_s_barrier();
        }

        #pragma unroll
        for (int m = 0; m < 2; m++) {
            #pragma unroll
            for (int n = 0; n < 4; n++) {
                int col = ncol0 + wn + n * 16 + l15;
                #pragma unroll
                for (int j = 0; j < 4; j++) {
                    int r = wm + m * 16 + q4 + j;
                    int tk = tokOut[r];
                    if (tk >= 0) out[(size_t)tk * D_ + col] = acc[m][n][j] * wBsh[r];
                }
            }
        }
    }
}

extern "C" void kernel_launch(void* const* d_in, const int* in_sizes, int n_in,
                              void* d_out, int out_size, void* d_ws, size_t ws_size,
                              hipStream_t stream) {
    const float* x  = (const float*)d_in[0];
    const float* Wg = (const float*)d_in[1];
    const float* We = (const float*)d_in[2];
    float* out = (float*)d_out;

    size_t off = 0;
    auto alloc = [&](size_t bytes) -> void* {
        void* p = (char*)d_ws + off;
        off += (bytes + 255) & ~(size_t)255;
        return p;
    };
    unsigned short* WeT  = (unsigned short*)alloc((size_t)E_ * 1024 * 1024 * 2);  // 16 MB
    unsigned short* Abf  = (unsigned short*)alloc((size_t)NTOK * D_ * 2);         // 16.8 MB
    int*   g_tok      = (int*)  alloc(NTOK * 4);
    float* wA_tok     = (float*)alloc(NTOK * 4);
    float* wB_tok     = (float*)alloc(NTOK * 4);
    int*   token_list = (int*)  alloc(NTOK * 4);
    float* wA_s       = (float*)alloc(NTOK * 4);
    float* wB_s       = (float*)alloc(NTOK * 4);
    int4*  tile_desc  = (int4*) alloc(MAX_TILES * 16);
    int*   n_tiles    = (int*)  alloc(4);

    prep_kernel<<<1024 + 2048, 256, 0, stream>>>(We, WeT, x, Wg, g_tok, wA_tok, wB_tok, Abf);
    route_kernel<<<64, 256, 0, stream>>>(g_tok, wA_tok, wB_tok,
                                         token_list, wA_s, wB_s, tile_desc, n_tiles);
    moe_gemm<<<dim3(8, MAX_TILES), 256, 0, stream>>>(Abf, WeT, token_list, wA_s, wB_s,
                                                     tile_desc, n_tiles, out);
}